// Round 2
// baseline (2502.900 us; speedup 1.0000x reference)
//
#include <hip/hip_runtime.h>

// Problem constants: B=2, S=1024, D=1024, H=16, DK=64
// N1 = B*S = 2048 (x rows), N2 = 4096 (enh rows), BH = 32, L = 2S = 2048
// ALL tensors are float32 (reference dtype).

// C[M x 1024] = A[M x 1024] @ W[1024 x 1024]^T + bias, optional relu.
// Tile 128x128, 256 threads, 8x8 per thread, BK=32.
// LDS row stride 36 words (mult of 4 for float4 stores; 36 mod 32 = 4 ->
// compute-phase reads are 2-way bank aliased = free on gfx950).
__global__ __launch_bounds__(256) void gemm_bias(
    const float* __restrict__ A, const float* __restrict__ W,
    const float* __restrict__ bias, float* __restrict__ C, int relu)
{
  __shared__ float As[128 * 36];
  __shared__ float Ws[128 * 36];
  const int tid = threadIdx.x;
  const int m0 = blockIdx.y * 128;
  const int n0 = blockIdx.x * 128;
  const int tx = tid & 15, ty = tid >> 4;
  const int lrow = tid >> 1, lc = (tid & 1) * 16;

  float acc[8][8];
#pragma unroll
  for (int i = 0; i < 8; ++i)
#pragma unroll
    for (int j = 0; j < 8; ++j) acc[i][j] = 0.f;

  for (int k0 = 0; k0 < 1024; k0 += 32) {
    __syncthreads();
    {
      const float4* ga = reinterpret_cast<const float4*>(A + (size_t)(m0 + lrow) * 1024 + k0 + lc);
      float4 a0 = ga[0], a1 = ga[1], a2 = ga[2], a3 = ga[3];
      float4* d = reinterpret_cast<float4*>(&As[lrow * 36 + lc]);
      d[0] = a0; d[1] = a1; d[2] = a2; d[3] = a3;
      const float4* gw = reinterpret_cast<const float4*>(W + (size_t)(n0 + lrow) * 1024 + k0 + lc);
      float4 w0 = gw[0], w1 = gw[1], w2 = gw[2], w3 = gw[3];
      float4* e = reinterpret_cast<float4*>(&Ws[lrow * 36 + lc]);
      e[0] = w0; e[1] = w1; e[2] = w2; e[3] = w3;
    }
    __syncthreads();
#pragma unroll 8
    for (int kk = 0; kk < 32; ++kk) {
      float a[8], b[8];
#pragma unroll
      for (int ii = 0; ii < 8; ++ii) a[ii] = As[(ty + 16 * ii) * 36 + kk];
#pragma unroll
      for (int jj = 0; jj < 8; ++jj) b[jj] = Ws[(tx + 16 * jj) * 36 + kk];
#pragma unroll
      for (int ii = 0; ii < 8; ++ii)
#pragma unroll
        for (int jj = 0; jj < 8; ++jj) acc[ii][jj] += a[ii] * b[jj];
    }
  }
#pragma unroll
  for (int ii = 0; ii < 8; ++ii) {
    const int m = m0 + ty + 16 * ii;
#pragma unroll
    for (int jj = 0; jj < 8; ++jj) {
      const int n = n0 + tx + 16 * jj;
      float v = acc[ii][jj] + bias[n];
      if (relu) v = fmaxf(v, 0.f);
      C[(size_t)m * 1024 + n] = v;
    }
  }
}

__global__ __launch_bounds__(256) void copy_kernel(const float4* __restrict__ s,
                                                   float4* __restrict__ d)
{
  const int i = blockIdx.x * 256 + threadIdx.x;
  d[i] = s[i];
}

// Attention for one (b,h) and a 32-row Q tile. L=2048 keys, DK=64.
// Phase A: scores (f32) -> attn output region (temporary), track row max.
// Phase B1: re-read scores (L2-hot), accumulate softmax denominator.
// Phase B2: re-read, write normalized attn (final output), accumulate ctx.
// ctx only needed for q rows >= 1024 (out = out[:, -S:, :]).
__global__ __launch_bounds__(256) void attn_kernel(
    const float* __restrict__ Q, const float* __restrict__ K,
    const float* __restrict__ V, float* __restrict__ attn, float* __restrict__ ctx)
{
  __shared__ float Qs[32][68];   // scaled Q tile (row stride 68: float4-aligned)
  __shared__ float KVs[64][68];  // K chunk, then V chunk
  __shared__ float Es[32][68];   // normalized p chunk
  __shared__ float mrow[32];
  __shared__ float invl[32];

  const int qt = blockIdx.x;     // 0..63
  const int bh = blockIdx.y;     // 0..31
  const int b = bh >> 4, h = bh & 15;
  const int q0 = qt * 32;
  const int tid = threadIdx.x;
  const int lane = tid & 63, w = tid >> 6;
  const int tx = tid & 15, ty = tid >> 4;
  const int i0 = ty * 2;         // 2 score rows per thread (phases A/B1)
  const int j0 = tx * 4;         // 4 score cols per thread
  const size_t base = (size_t)b * 2048 * 1024 + (size_t)h * 64;
  float* arow = attn + ((size_t)bh * 2048 + q0) * 2048;

  {  // load Q tile, fold in 1/sqrt(64)
    const int i = tid >> 3, d0 = (tid & 7) * 8;
    const float4* g = reinterpret_cast<const float4*>(Q + base + (size_t)(q0 + i) * 1024 + d0);
    float4 v0 = g[0], v1 = g[1];
    Qs[i][d0 + 0] = v0.x * 0.125f; Qs[i][d0 + 1] = v0.y * 0.125f;
    Qs[i][d0 + 2] = v0.z * 0.125f; Qs[i][d0 + 3] = v0.w * 0.125f;
    Qs[i][d0 + 4] = v1.x * 0.125f; Qs[i][d0 + 5] = v1.y * 0.125f;
    Qs[i][d0 + 6] = v1.z * 0.125f; Qs[i][d0 + 7] = v1.w * 0.125f;
  }

  float m0v = -3.0e38f, m1v = -3.0e38f;

  // ---- Phase A: scores ----
  for (int kc = 0; kc < 2048; kc += 64) {
    __syncthreads();
    {  // load K chunk (64x64)
      const int j = tid >> 2, d0 = (tid & 3) * 16;
      const float4* g = reinterpret_cast<const float4*>(K + base + (size_t)(kc + j) * 1024 + d0);
      float4 v0 = g[0], v1 = g[1], v2 = g[2], v3 = g[3];
      float4* dst = reinterpret_cast<float4*>(&KVs[j][d0]);
      dst[0] = v0; dst[1] = v1; dst[2] = v2; dst[3] = v3;
    }
    __syncthreads();
    const float4* qa = reinterpret_cast<const float4*>(&Qs[i0][0]);
    const float4* qb = reinterpret_cast<const float4*>(&Qs[i0 + 1][0]);
    const float4* k0p = reinterpret_cast<const float4*>(&KVs[j0][0]);
    const float4* k1p = reinterpret_cast<const float4*>(&KVs[j0 + 1][0]);
    const float4* k2p = reinterpret_cast<const float4*>(&KVs[j0 + 2][0]);
    const float4* k3p = reinterpret_cast<const float4*>(&KVs[j0 + 3][0]);
    float s00 = 0, s01 = 0, s02 = 0, s03 = 0, s10 = 0, s11 = 0, s12 = 0, s13 = 0;
#pragma unroll
    for (int d4 = 0; d4 < 16; ++d4) {
      float4 a0 = qa[d4], a1 = qb[d4];
      float4 b0 = k0p[d4], b1 = k1p[d4], b2 = k2p[d4], b3 = k3p[d4];
      s00 += a0.x * b0.x + a0.y * b0.y + a0.z * b0.z + a0.w * b0.w;
      s01 += a0.x * b1.x + a0.y * b1.y + a0.z * b1.z + a0.w * b1.w;
      s02 += a0.x * b2.x + a0.y * b2.y + a0.z * b2.z + a0.w * b2.w;
      s03 += a0.x * b3.x + a0.y * b3.y + a0.z * b3.z + a0.w * b3.w;
      s10 += a1.x * b0.x + a1.y * b0.y + a1.z * b0.z + a1.w * b0.w;
      s11 += a1.x * b1.x + a1.y * b1.y + a1.z * b1.z + a1.w * b1.w;
      s12 += a1.x * b2.x + a1.y * b2.y + a1.z * b2.z + a1.w * b2.w;
      s13 += a1.x * b3.x + a1.y * b3.y + a1.z * b3.z + a1.w * b3.w;
    }
    float4 o0; o0.x = s00; o0.y = s01; o0.z = s02; o0.w = s03;
    *reinterpret_cast<float4*>(arow + (size_t)i0 * 2048 + kc + j0) = o0;
    float4 o1; o1.x = s10; o1.y = s11; o1.z = s12; o1.w = s13;
    *reinterpret_cast<float4*>(arow + (size_t)(i0 + 1) * 2048 + kc + j0) = o1;
    m0v = fmaxf(m0v, fmaxf(fmaxf(s00, s01), fmaxf(s02, s03)));
    m1v = fmaxf(m1v, fmaxf(fmaxf(s10, s11), fmaxf(s12, s13)));
  }

  // reduce max over the 16 lanes sharing a row group (within one wave)
#pragma unroll
  for (int off = 1; off < 16; off <<= 1) {
    m0v = fmaxf(m0v, __shfl_xor(m0v, off, 64));
    m1v = fmaxf(m1v, __shfl_xor(m1v, off, 64));
  }

  // ---- Phase B1: denominators (re-read own scores; same thread wrote them) ----
  float l0 = 0.f, l1 = 0.f;
  for (int kc = 0; kc < 2048; kc += 64) {
    float4 r0 = *reinterpret_cast<const float4*>(arow + (size_t)i0 * 2048 + kc + j0);
    float4 r1 = *reinterpret_cast<const float4*>(arow + (size_t)(i0 + 1) * 2048 + kc + j0);
    l0 += __expf(r0.x - m0v) + __expf(r0.y - m0v) + __expf(r0.z - m0v) + __expf(r0.w - m0v);
    l1 += __expf(r1.x - m1v) + __expf(r1.y - m1v) + __expf(r1.z - m1v) + __expf(r1.w - m1v);
  }
#pragma unroll
  for (int off = 1; off < 16; off <<= 1) {
    l0 += __shfl_xor(l0, off, 64);
    l1 += __shfl_xor(l1, off, 64);
  }
  if ((lane & 15) == 0) {
    mrow[i0] = m0v; mrow[i0 + 1] = m1v;
    invl[i0] = 1.f / l0; invl[i0 + 1] = 1.f / l1;
  }
  __syncthreads();

  // ---- Phase B2: write normalized attn, accumulate ctx ----
  const bool needCtx = (q0 >= 1024);
  float acc[8];
#pragma unroll
  for (int ii = 0; ii < 8; ++ii) acc[ii] = 0.f;

  for (int kc = 0; kc < 2048; kc += 64) {
    __syncthreads();
    if (needCtx) {  // load V chunk
      const int j = tid >> 2, d0 = (tid & 3) * 16;
      const float4* g = reinterpret_cast<const float4*>(V + base + (size_t)(kc + j) * 1024 + d0);
      float4 v0 = g[0], v1 = g[1], v2 = g[2], v3 = g[3];
      float4* dst = reinterpret_cast<float4*>(&KVs[j][d0]);
      dst[0] = v0; dst[1] = v1; dst[2] = v2; dst[3] = v3;
    }
    {  // read scores chunk, normalize, write final attn + stage p in LDS
      const int i = tid >> 3, jj0 = (tid & 7) * 8;
      float* p = arow + (size_t)i * 2048 + kc + jj0;
      float4 v0 = reinterpret_cast<const float4*>(p)[0];
      float4 v1 = reinterpret_cast<const float4*>(p)[1];
      const float mi = mrow[i], il = invl[i];
      float p0 = __expf(v0.x - mi) * il, p1 = __expf(v0.y - mi) * il;
      float p2 = __expf(v0.z - mi) * il, p3 = __expf(v0.w - mi) * il;
      float p4 = __expf(v1.x - mi) * il, p5 = __expf(v1.y - mi) * il;
      float p6 = __expf(v1.z - mi) * il, p7 = __expf(v1.w - mi) * il;
      Es[i][jj0 + 0] = p0; Es[i][jj0 + 1] = p1; Es[i][jj0 + 2] = p2; Es[i][jj0 + 3] = p3;
      Es[i][jj0 + 4] = p4; Es[i][jj0 + 5] = p5; Es[i][jj0 + 6] = p6; Es[i][jj0 + 7] = p7;
      float4 w0; w0.x = p0; w0.y = p1; w0.z = p2; w0.w = p3;
      float4 w1; w1.x = p4; w1.y = p5; w1.z = p6; w1.w = p7;
      reinterpret_cast<float4*>(p)[0] = w0;
      reinterpret_cast<float4*>(p)[1] = w1;
    }
    __syncthreads();
    if (needCtx) {
#pragma unroll 8
      for (int j = 0; j < 64; ++j) {
        const float v = KVs[j][lane];
#pragma unroll
        for (int ii = 0; ii < 8; ++ii) acc[ii] += Es[w * 8 + ii][j] * v;
      }
    }
  }
  if (needCtx) {
#pragma unroll
    for (int ii = 0; ii < 8; ++ii) {
      const int i = w * 8 + ii;
      ctx[base + (size_t)(q0 + i) * 1024 + lane] = acc[ii];
    }
  }
}

extern "C" void kernel_launch(void* const* d_in, const int* in_sizes, int n_in,
                              void* d_out, int out_size, void* d_ws, size_t ws_size,
                              hipStream_t stream) {
  (void)in_sizes; (void)n_in; (void)out_size; (void)ws_size;
  const float* x   = (const float*)d_in[0];
  const float* Wq  = (const float*)d_in[1];
  const float* bq  = (const float*)d_in[2];
  const float* Wk  = (const float*)d_in[3];
  const float* bk  = (const float*)d_in[4];
  const float* Wv  = (const float*)d_in[5];
  const float* bv  = (const float*)d_in[6];
  const float* Wo  = (const float*)d_in[7];
  const float* bo  = (const float*)d_in[8];
  const float* M1  = (const float*)d_in[9];
  const float* bm1 = (const float*)d_in[10];
  const float* M2  = (const float*)d_in[11];
  const float* bm2 = (const float*)d_in[12];

  float* ws  = (float*)d_ws;
  float* h   = ws;                         // 2048*1024
  float* enh = h + (size_t)2048 * 1024;    // 4096*1024
  float* Qb  = enh + (size_t)4096 * 1024;  // 4096*1024
  float* Kb  = Qb + (size_t)4096 * 1024;   // 4096*1024
  float* Vb  = Kb + (size_t)4096 * 1024;   // 4096*1024
  float* ctx = Vb + (size_t)4096 * 1024;   // 4096*1024   (total 88 MB)

  float* out  = (float*)d_out;                    // (2,1024,1024)
  float* attn = out + (size_t)2 * 1024 * 1024;    // (2,16,2048,2048)

  // FFN: h = relu(x@M1^T+bm1); mem = h@M2^T+bm2 -> enh[0:2048]
  gemm_bias<<<dim3(8, 16), 256, 0, stream>>>(x, M1, bm1, h, 1);
  gemm_bias<<<dim3(8, 16), 256, 0, stream>>>(h, M2, bm2, enh, 0);
  // enh[2048:4096] = x
  copy_kernel<<<dim3(2048), 256, 0, stream>>>(
      reinterpret_cast<const float4*>(x),
      reinterpret_cast<float4*>(enh + (size_t)2048 * 1024));
  // Q/K/V = enh @ W^T + b
  gemm_bias<<<dim3(8, 32), 256, 0, stream>>>(enh, Wq, bq, Qb, 0);
  gemm_bias<<<dim3(8, 32), 256, 0, stream>>>(enh, Wk, bk, Kb, 0);
  gemm_bias<<<dim3(8, 32), 256, 0, stream>>>(enh, Wv, bv, Vb, 0);
  // attention (writes attn output + ctx)
  attn_kernel<<<dim3(64, 32), 256, 0, stream>>>(Qb, Kb, Vb, attn, ctx);
  // out = ctx[:, -1024:, :] @ Wo^T + bo  (rows 1024..2047 and 3072..4095 of ctx)
  gemm_bias<<<dim3(8, 8), 256, 0, stream>>>(ctx + (size_t)1024 * 1024, Wo, bo, out, 0);
  gemm_bias<<<dim3(8, 8), 256, 0, stream>>>(ctx + (size_t)3072 * 1024, Wo, bo,
                                            out + (size_t)1024 * 1024, 0);
}